// Round 17
// baseline (716.737 us; speedup 1.0000x reference)
//
#include <hip/hip_runtime.h>

#define T_STEPS 1000
#define DT 0.1f
#define HIDDEN 128
#define N_AGENTS 1024

typedef float v2f __attribute__((ext_vector_type(2)));

// tanh(x) = 1 - 2/(exp(2x)+1); exact at +/-inf, ~1e-7 rel error.
__device__ __forceinline__ float tanh_fast(float x) {
    float e = __expf(2.0f * x);
    return 1.0f - 2.0f * __builtin_amdgcn_rcpf(e + 1.0f);
}

// Opaque 8B load (R13-R16 proven residency mechanism).
__device__ __forceinline__ v2f opaque_load8(const float* p) {
    v2f v;
    asm volatile("global_load_dwordx2 %0, %1, off\n\ts_waitcnt vmcnt(0)"
                 : "=v"(v)
                 : "v"((unsigned long long)(uintptr_t)p)
                 : "memory");
    return v;
}

__device__ __forceinline__ float uniformf(float v) {
    return __builtin_bit_cast(float,
        __builtin_amdgcn_readfirstlane(__builtin_bit_cast(int, v)));
}

// 64-lane sum on the VALU pipe via DPP row ops (R11-R16 verified).
__device__ __forceinline__ float wave_sum_dpp(float x) {
    float t;
    #define DPPADD(ctrl, rmask)                                              \
        t = __builtin_bit_cast(float, __builtin_amdgcn_update_dpp(           \
                0, __builtin_bit_cast(int, x), ctrl, rmask, 0xf, false));    \
        x += t;
    DPPADD(0x111, 0xf)
    DPPADD(0x112, 0xf)
    DPPADD(0x114, 0xf)
    DPPADD(0x118, 0xf)
    DPPADD(0x142, 0xa)
    DPPADD(0x143, 0xc)
    #undef DPPADD
    return __builtin_bit_cast(float,
        __builtin_amdgcn_readlane(__builtin_bit_cast(int, x), 63));
}

// Pre-pack W1 into component-paired layout (R14-R16 verified).
__global__ void pack_kernel(const float* __restrict__ W1,
                            float* __restrict__ pw) {
    const int row = blockIdx.x;     // 128
    const int a   = threadIdx.x;    // 32
    const float* rp = W1 + row * 128;
    float* out = pw + row * 128;
    out[2*a]          = rp[3*a];
    out[2*a + 1]      = rp[3*a + 1];
    out[64 + 2*a]     = rp[3*a + 2];
    out[64 + 2*a + 1] = rp[96 + a];
}

// R16 role-asymmetric 2-wave agent + 8-STEP BARRIER WINDOWS.
// R16 ran 1 barrier/step (1000 barriers) with h1's dependencies holding
// 8+ steps of slack. Now: ONE __syncthreads per 8-step window (125 total).
//  h=0 (consumer): unchanged — consume slot t&15, DPP layer-2 (in-wave
//    broadcast), tail once, publish e(t+1) -> e4buf[(t+1)&15], push e(t+1).
//  h=1 (producer): pushes 7-step-delayed state e(t-7) read from
//    e4buf[(t+9)&15] — every state it touches in window w was published in
//    window w-1 (h0 writes e(8w) at t=8w-1), so one barrier/window makes
//    all reads race-free. Partial for s complete at t=s-9, shipped to
//    part1[(t+9)&31], consumed >=1 window later. Slot-reuse gaps >=2
//    windows. Accumulation order per slot (descending k) identical to R16.
__global__ __launch_bounds__(128)
__attribute__((amdgpu_waves_per_eu(1, 2)))
void sim_kernel(const float* __restrict__ target_pos,
                const float* __restrict__ logsigma,
                const float* __restrict__ x_inits,
                const float* __restrict__ pw,
                const float* __restrict__ b1,
                const float* __restrict__ W2,
                const float* __restrict__ b2,
                float2* __restrict__ ws) {
    const int agent = blockIdx.x;
    const int tid  = threadIdx.x;   // 0..127
    const int h    = tid >> 6;      // 0 = consumer, 1 = producer
    const int lane = tid & 63;
    const int rowA = lane;
    const int rowB = lane + 64;

    __shared__ float2 part1[32][64];        // h=1 -> h=0 partial ring
    __shared__ float4 e4buf[16];            // state ring, 16-deep (9 live)

    const float tx0 = uniformf(target_pos[0]), ty0 = uniformf(target_pos[1]);
    const float tx1 = uniformf(target_pos[2]), ty1 = uniformf(target_pos[3]);
    const float tx2 = uniformf(target_pos[4]), ty2 = uniformf(target_pos[5]);
    const float is0 = uniformf(1.0f / expf(logsigma[0]));
    const float is1 = uniformf(1.0f / expf(logsigma[1]));
    const float is2 = uniformf(1.0f / expf(logsigma[2]));

    // Paired weights for ages 16h..16h+15, rows A and B: 64 v2f pinned.
    v2f WxyA[16], WzcA[16], WxyB[16], WzcB[16];
    {
        const float* baseA = pw + rowA * 128;
        const float* baseB = pw + rowB * 128;
        #pragma unroll
        for (int i = 0; i < 16; ++i) {
            WxyA[i] = opaque_load8(baseA + 32 * h + 2 * i);
            WzcA[i] = opaque_load8(baseA + 64 + 32 * h + 2 * i);
            WxyB[i] = opaque_load8(baseB + 32 * h + 2 * i);
            WzcB[i] = opaque_load8(baseB + 64 + 32 * h + 2 * i);
        }
    }
    const float b1A = b1[rowA], b1B = b1[rowB];
    const float w20A = W2[rowA], w20B = W2[rowB];
    const float w21A = W2[HIDDEN + rowA], w21B = W2[HIDDEN + rowB];
    const float b2x = uniformf(b2[0]), b2y = uniformf(b2[1]);

    auto conc = [&](float px, float py) {
        float dx0 = px - tx0, dy0 = py - ty0;
        float dx1 = px - tx1, dy1 = py - ty1;
        float dx2 = px - tx2, dy2 = py - ty2;
        float cc  = is0 * __expf(-(dx0*dx0 + dy0*dy0) * is0);
        cc       += is1 * __expf(-(dx1*dx1 + dy1*dy1) * is1);
        cc       += is2 * __expf(-(dx2*dx2 + dy2*dy2) * is2);
        return cc;
    };

    float x  = uniformf(x_inits[3 * agent]);
    float y  = uniformf(x_inits[3 * agent + 1]);
    float th = uniformf(x_inits[3 * agent + 2]);
    float c  = conc(x, y);

    v2f RA[16], RB[16];
    {
        v2f exy0 = {x, y}, ezc0 = {th, c};
        if (h == 0) {
            // seed slot s (s=0..15): sum_{k=s..15} W[k]·e(0)
            v2f aA = {0.f,0.f}, aB = {0.f,0.f};
            #pragma unroll
            for (int k = 15; k >= 0; --k) {
                aA = WxyA[k]*exy0 + aA;  aA = WzcA[k]*ezc0 + aA;
                aB = WxyB[k]*exy0 + aB;  aB = WzcB[k]*ezc0 + aB;
                RA[k] = aA;  RB[k] = aB;
            }
            if (lane == 0) {
                // h=1 reads e(t-7) at t=0..7 -> slots (t+9)&15 = 9..15,0
                float4 e0 = make_float4(x, y, th, c);
                #pragma unroll
                for (int m = 9; m < 16; ++m) e4buf[m] = e0;
                e4buf[0] = e0;
            }
        } else {
            // Seed for d=7: slot (s&15), s in [9,24): sum_{k=s-8..15} W[k]·e0
            // (descending-k accumulation; slot for s=k+8 stored after k).
            RA[8] = (v2f){0.f,0.f};  RB[8] = (v2f){0.f,0.f};
            v2f aA = {0.f,0.f}, aB = {0.f,0.f};
            #pragma unroll
            for (int k = 15; k >= 1; --k) {
                aA = WxyA[k]*exy0 + aA;  aA = WzcA[k]*ezc0 + aA;
                aB = WxyB[k]*exy0 + aB;  aB = WzcB[k]*ezc0 + aB;
                RA[(k+8)&15] = aA;  RB[(k+8)&15] = aB;
            }
            // part1 prefill for s=0..8 (never shipped in-loop): full sum.
            v2f fA = WxyA[0]*exy0 + aA;  fA = WzcA[0]*ezc0 + fA;
            v2f fB = WxyB[0]*exy0 + aB;  fB = WzcB[0]*ezc0 + fB;
            float2 full = make_float2(fA.x + fA.y, fB.x + fB.y);
            #pragma unroll
            for (int s = 0; s <= 8; ++s) part1[s][lane] = full;
        }
    }
    __syncthreads();

    float S_c = 0.f, S_u = 0.f;

    if (h == 0) {
        float2 pl = part1[0][lane];   // partial_1 for step 0
        auto h0_step = [&](int t, int j) {
            // consume slot j (= t mod 16)
            float hA = fmaxf((RA[j].x + RA[j].y) + pl.x + b1A, 0.f);
            float hB = fmaxf((RB[j].x + RB[j].y) + pl.y + b1B, 0.f);
            float s0 = wave_sum_dpp(fmaf(w20A, hA, w20B * hB));
            float s1 = wave_sum_dpp(fmaf(w21A, hA, w21B * hB));
            float v  = tanh_fast(s0 + b2x);
            float wv = tanh_fast(s1 + b2y);
            S_u += v * v + wv * wv;
            float sn = __sinf(th), cs = __cosf(th);
            float dv = DT * v;
            x  = fmaf(dv, cs, x);
            y  = fmaf(dv, sn, y);
            th = fmaf(DT, wv, th);
            c  = conc(x, y);
            S_c += c;
            if (lane == 0) e4buf[(t + 1) & 15] = make_float4(x, y, th, c);
            v2f exy = {x, y}, ezc = {th, c};
            // push e(t+1): k=15 assigns slot j; k=0..14 accumulate
            RA[j] = WxyA[15] * exy;  RA[j] = WzcA[15] * ezc + RA[j];
            RB[j] = WxyB[15] * exy;  RB[j] = WzcB[15] * ezc + RB[j];
            #pragma unroll
            for (int k = 0; k < 15; ++k) {
                const int m = (j + 1 + k) & 15;
                RA[m] = WxyA[k] * exy + RA[m];  RA[m] = WzcA[k] * ezc + RA[m];
                RB[m] = WxyB[k] * exy + RB[m];  RB[m] = WzcB[k] * ezc + RB[m];
            }
            pl = part1[(t + 1) & 31][lane];   // prefetch next partial
        };
        #pragma unroll 1
        for (int tt = 0; tt < 62; ++tt) {
            const int tb = tt * 16;
            __syncthreads();
            #pragma unroll
            for (int j = 0; j < 8; ++j) h0_step(tb + j, j);
            __syncthreads();
            #pragma unroll
            for (int j = 8; j < 16; ++j) h0_step(tb + j, j);
        }
        __syncthreads();
        #pragma unroll
        for (int j = 0; j < 8; ++j) h0_step(992 + j, j);

        if (lane == 0) ws[agent] = make_float2(S_c, S_u);
    } else {
        auto h1_step = [&](int t, int j) {
            // state e(t-7): published in a previous window
            float4 e = e4buf[(j + 9) & 15];
            v2f exy = {e.x, e.y}, ezc = {e.z, e.w};
            // push e(t-7): k=15 assigns slot (j+8); k=0..14 accumulate
            {
                const int m = (j + 8) & 15;
                RA[m] = WxyA[15] * exy;  RA[m] = WzcA[15] * ezc + RA[m];
                RB[m] = WxyB[15] * exy;  RB[m] = WzcB[15] * ezc + RB[m];
            }
            #pragma unroll
            for (int k = 0; k < 15; ++k) {
                const int m = (j + 9 + k) & 15;
                RA[m] = WxyA[k] * exy + RA[m];  RA[m] = WzcA[k] * ezc + RA[m];
                RB[m] = WxyB[k] * exy + RB[m];  RB[m] = WzcB[k] * ezc + RB[m];
            }
            // ship partial for s = t+9 (slot j+9, just completed by k=0)
            {
                const int m = (j + 9) & 15;
                part1[(t + 9) & 31][lane] =
                    make_float2(RA[m].x + RA[m].y, RB[m].x + RB[m].y);
            }
        };
        #pragma unroll 1
        for (int tt = 0; tt < 62; ++tt) {
            const int tb = tt * 16;
            __syncthreads();
            #pragma unroll
            for (int j = 0; j < 8; ++j) h1_step(tb + j, j);
            __syncthreads();
            #pragma unroll
            for (int j = 8; j < 16; ++j) h1_step(tb + j, j);
        }
        __syncthreads();
        #pragma unroll
        for (int j = 0; j < 8; ++j) h1_step(992 + j, j);
    }
}

__global__ void reduce_kernel(const float2* __restrict__ ws,
                              float* __restrict__ out) {
    const int tid = threadIdx.x;  // 256 threads
    float sc = 0.f, su = 0.f;
    for (int i = tid; i < N_AGENTS; i += 256) {
        float2 v = ws[i];
        sc += v.x;
        su += v.y;
    }
    #pragma unroll
    for (int off = 32; off > 0; off >>= 1) {
        sc += __shfl_xor(sc, off);
        su += __shfl_xor(su, off);
    }
    __shared__ float2 partw[4];
    int wave = tid >> 6;
    if ((tid & 63) == 0) partw[wave] = make_float2(sc, su);
    __syncthreads();
    if (tid == 0) {
        float SC = partw[0].x + partw[1].x + partw[2].x + partw[3].x;
        float SU = partw[0].y + partw[1].y + partw[2].y + partw[3].y;
        const float invNT  = 1.0f / (float)(N_AGENTS * T_STEPS);
        const float invNT2 = 1.0f / (float)(N_AGENTS * T_STEPS * 2);
        out[0] = -SC * invNT + SU * invNT2;
    }
}

extern "C" void kernel_launch(void* const* d_in, const int* in_sizes, int n_in,
                              void* d_out, int out_size, void* d_ws, size_t ws_size,
                              hipStream_t stream) {
    const float* target_pos = (const float*)d_in[0];
    const float* logsigma   = (const float*)d_in[1];
    const float* x_inits    = (const float*)d_in[2];
    const float* W1         = (const float*)d_in[3];
    const float* b1         = (const float*)d_in[4];
    const float* W2         = (const float*)d_in[5];
    const float* b2         = (const float*)d_in[6];

    float*  pw   = (float*)d_ws;                          // 64 KB packed W1
    float2* sums = (float2*)((char*)d_ws + 64 * 1024);    // per-agent sums

    pack_kernel<<<HIDDEN, 32, 0, stream>>>(W1, pw);
    sim_kernel<<<N_AGENTS, 128, 0, stream>>>(target_pos, logsigma, x_inits,
                                             pw, b1, W2, b2, sums);
    reduce_kernel<<<1, 256, 0, stream>>>(sums, (float*)d_out);
}

// Round 18
// 655.300 us; speedup vs baseline: 1.0938x; 1.0938x over previous
//
#include <hip/hip_runtime.h>

#define T_STEPS 1000
#define DT 0.1f
#define HIDDEN 128
#define N_AGENTS 1024

typedef float v2f __attribute__((ext_vector_type(2)));

// tanh(x) = 1 - 2/(exp(2x)+1); exact at +/-inf, ~1e-7 rel error.
__device__ __forceinline__ float tanh_fast(float x) {
    float e = __expf(2.0f * x);
    return 1.0f - 2.0f * __builtin_amdgcn_rcpf(e + 1.0f);
}

// Opaque 8B load (R13-R17 proven residency mechanism).
__device__ __forceinline__ v2f opaque_load8(const float* p) {
    v2f v;
    asm volatile("global_load_dwordx2 %0, %1, off\n\ts_waitcnt vmcnt(0)"
                 : "=v"(v)
                 : "v"((unsigned long long)(uintptr_t)p)
                 : "memory");
    return v;
}

__device__ __forceinline__ float uniformf(float v) {
    return __builtin_bit_cast(float,
        __builtin_amdgcn_readfirstlane(__builtin_bit_cast(int, v)));
}

// 64-lane sum on the VALU pipe via DPP row ops (R11-R17 verified).
__device__ __forceinline__ float wave_sum_dpp(float x) {
    float t;
    #define DPPADD(ctrl, rmask)                                              \
        t = __builtin_bit_cast(float, __builtin_amdgcn_update_dpp(           \
                0, __builtin_bit_cast(int, x), ctrl, rmask, 0xf, false));    \
        x += t;
    DPPADD(0x111, 0xf)
    DPPADD(0x112, 0xf)
    DPPADD(0x114, 0xf)
    DPPADD(0x118, 0xf)
    DPPADD(0x142, 0xa)
    DPPADD(0x143, 0xc)
    #undef DPPADD
    return __builtin_bit_cast(float,
        __builtin_amdgcn_readlane(__builtin_bit_cast(int, x), 63));
}

// Pre-pack W1 into component-paired layout (R14-R17 verified).
__global__ void pack_kernel(const float* __restrict__ W1,
                            float* __restrict__ pw) {
    const int row = blockIdx.x;     // 128
    const int a   = threadIdx.x;    // 32
    const float* rp = W1 + row * 128;
    float* out = pw + row * 128;
    out[2*a]          = rp[3*a];
    out[2*a + 1]      = rp[3*a + 1];
    out[64 + 2*a]     = rp[3*a + 2];
    out[64 + 2*a + 1] = rp[96 + a];
}

// R17 structure (role-asymmetric 2-wave agent, 8-step barrier windows,
// mod-16 ring) with the OCCUPANCY CLIFF fixed:
//  - R17 post-mortem: VGPR 132 + 128 pinned weight regs = 260 > 256 ->
//    1 wave/SIMD (11.6% occ) -> 2 grid passes. Per-wave throughput had
//    DOUBLED (358 us/pass); we lost only the cliff.
//  - waves_per_eu(2,2): hard 256-unified budget -> allocator must find a
//    <=128-arch allocation (R16 proved one exists for this body).
//  - Register diet: all LDS ring indices are compile-time ((j+1)&15,
//    (j+9)&15) or SGPR-parity (s16 = (tt&1)<<4) — the live `t` counter
//    and its per-lane address math are gone from the loop.
__global__ __launch_bounds__(128)
__attribute__((amdgpu_waves_per_eu(2, 2)))
void sim_kernel(const float* __restrict__ target_pos,
                const float* __restrict__ logsigma,
                const float* __restrict__ x_inits,
                const float* __restrict__ pw,
                const float* __restrict__ b1,
                const float* __restrict__ W2,
                const float* __restrict__ b2,
                float2* __restrict__ ws) {
    const int agent = blockIdx.x;
    const int tid  = threadIdx.x;   // 0..127
    const int h    = tid >> 6;      // 0 = consumer, 1 = producer
    const int lane = tid & 63;
    const int rowA = lane;
    const int rowB = lane + 64;

    __shared__ float2 part1[32][64];        // h=1 -> h=0 partial ring
    __shared__ float4 e4buf[16];            // state ring, 16-deep (9 live)

    const float tx0 = uniformf(target_pos[0]), ty0 = uniformf(target_pos[1]);
    const float tx1 = uniformf(target_pos[2]), ty1 = uniformf(target_pos[3]);
    const float tx2 = uniformf(target_pos[4]), ty2 = uniformf(target_pos[5]);
    const float is0 = uniformf(1.0f / expf(logsigma[0]));
    const float is1 = uniformf(1.0f / expf(logsigma[1]));
    const float is2 = uniformf(1.0f / expf(logsigma[2]));

    // Paired weights for ages 16h..16h+15, rows A and B: 64 v2f pinned.
    v2f WxyA[16], WzcA[16], WxyB[16], WzcB[16];
    {
        const float* baseA = pw + rowA * 128;
        const float* baseB = pw + rowB * 128;
        #pragma unroll
        for (int i = 0; i < 16; ++i) {
            WxyA[i] = opaque_load8(baseA + 32 * h + 2 * i);
            WzcA[i] = opaque_load8(baseA + 64 + 32 * h + 2 * i);
            WxyB[i] = opaque_load8(baseB + 32 * h + 2 * i);
            WzcB[i] = opaque_load8(baseB + 64 + 32 * h + 2 * i);
        }
    }
    const float b1A = b1[rowA], b1B = b1[rowB];
    const float w20A = W2[rowA], w20B = W2[rowB];
    const float w21A = W2[HIDDEN + rowA], w21B = W2[HIDDEN + rowB];
    const float b2x = uniformf(b2[0]), b2y = uniformf(b2[1]);

    auto conc = [&](float px, float py) {
        float dx0 = px - tx0, dy0 = py - ty0;
        float dx1 = px - tx1, dy1 = py - ty1;
        float dx2 = px - tx2, dy2 = py - ty2;
        float cc  = is0 * __expf(-(dx0*dx0 + dy0*dy0) * is0);
        cc       += is1 * __expf(-(dx1*dx1 + dy1*dy1) * is1);
        cc       += is2 * __expf(-(dx2*dx2 + dy2*dy2) * is2);
        return cc;
    };

    float x  = uniformf(x_inits[3 * agent]);
    float y  = uniformf(x_inits[3 * agent + 1]);
    float th = uniformf(x_inits[3 * agent + 2]);
    float c  = conc(x, y);

    v2f RA[16], RB[16];
    {
        v2f exy0 = {x, y}, ezc0 = {th, c};
        if (h == 0) {
            // seed slot s (s=0..15): sum_{k=s..15} W[k]·e(0)
            v2f aA = {0.f,0.f}, aB = {0.f,0.f};
            #pragma unroll
            for (int k = 15; k >= 0; --k) {
                aA = WxyA[k]*exy0 + aA;  aA = WzcA[k]*ezc0 + aA;
                aB = WxyB[k]*exy0 + aB;  aB = WzcB[k]*ezc0 + aB;
                RA[k] = aA;  RB[k] = aB;
            }
            if (lane == 0) {
                // h=1 reads e(t-7) at t=0..7 -> slots (t+9)&15 = 9..15,0
                float4 e0 = make_float4(x, y, th, c);
                #pragma unroll
                for (int m = 9; m < 16; ++m) e4buf[m] = e0;
                e4buf[0] = e0;
            }
        } else {
            // Seed for d=7: slot (s&15), s in [9,24): sum_{k=s-8..15} W[k]·e0
            RA[8] = (v2f){0.f,0.f};  RB[8] = (v2f){0.f,0.f};
            v2f aA = {0.f,0.f}, aB = {0.f,0.f};
            #pragma unroll
            for (int k = 15; k >= 1; --k) {
                aA = WxyA[k]*exy0 + aA;  aA = WzcA[k]*ezc0 + aA;
                aB = WxyB[k]*exy0 + aB;  aB = WzcB[k]*ezc0 + aB;
                RA[(k+8)&15] = aA;  RB[(k+8)&15] = aB;
            }
            // part1 prefill for s=0..8: full 16-age e(0) sum.
            v2f fA = WxyA[0]*exy0 + aA;  fA = WzcA[0]*ezc0 + fA;
            v2f fB = WxyB[0]*exy0 + aB;  fB = WzcB[0]*ezc0 + fB;
            float2 full = make_float2(fA.x + fA.y, fB.x + fB.y);
            #pragma unroll
            for (int s = 0; s <= 8; ++s) part1[s][lane] = full;
        }
    }
    __syncthreads();

    float S_c = 0.f, S_u = 0.f;

    if (h == 0) {
        float2 pl = part1[0][lane];   // partial_1 for step 0
        // s16 = window parity << 4 (SGPR); part1 index (s16+j+1)&31.
        auto h0_step = [&](int j, int s16) {
            float hA = fmaxf((RA[j].x + RA[j].y) + pl.x + b1A, 0.f);
            float hB = fmaxf((RB[j].x + RB[j].y) + pl.y + b1B, 0.f);
            float s0 = wave_sum_dpp(fmaf(w20A, hA, w20B * hB));
            float s1 = wave_sum_dpp(fmaf(w21A, hA, w21B * hB));
            float v  = tanh_fast(s0 + b2x);
            float wv = tanh_fast(s1 + b2y);
            S_u += v * v + wv * wv;
            float sn = __sinf(th), cs = __cosf(th);
            float dv = DT * v;
            x  = fmaf(dv, cs, x);
            y  = fmaf(dv, sn, y);
            th = fmaf(DT, wv, th);
            c  = conc(x, y);
            S_c += c;
            if (lane == 0) e4buf[(j + 1) & 15] = make_float4(x, y, th, c);
            v2f exy = {x, y}, ezc = {th, c};
            RA[j] = WxyA[15] * exy;  RA[j] = WzcA[15] * ezc + RA[j];
            RB[j] = WxyB[15] * exy;  RB[j] = WzcB[15] * ezc + RB[j];
            #pragma unroll
            for (int k = 0; k < 15; ++k) {
                const int m = (j + 1 + k) & 15;
                RA[m] = WxyA[k] * exy + RA[m];  RA[m] = WzcA[k] * ezc + RA[m];
                RB[m] = WxyB[k] * exy + RB[m];  RB[m] = WzcB[k] * ezc + RB[m];
            }
            pl = part1[(s16 + j + 1) & 31][lane];
        };
        #pragma unroll 1
        for (int tt = 0; tt < 62; ++tt) {
            const int s16 = (tt & 1) << 4;
            __syncthreads();
            #pragma unroll
            for (int j = 0; j < 8; ++j) h0_step(j, s16);
            __syncthreads();
            #pragma unroll
            for (int j = 8; j < 16; ++j) h0_step(j, s16);
        }
        __syncthreads();
        #pragma unroll
        for (int j = 0; j < 8; ++j) h0_step(j, 0);

        if (lane == 0) ws[agent] = make_float2(S_c, S_u);
    } else {
        auto h1_step = [&](int j, int s16) {
            float4 e = e4buf[(j + 9) & 15];   // state e(t-7), prev window
            v2f exy = {e.x, e.y}, ezc = {e.z, e.w};
            {
                const int m = (j + 8) & 15;
                RA[m] = WxyA[15] * exy;  RA[m] = WzcA[15] * ezc + RA[m];
                RB[m] = WxyB[15] * exy;  RB[m] = WzcB[15] * ezc + RB[m];
            }
            #pragma unroll
            for (int k = 0; k < 15; ++k) {
                const int m = (j + 9 + k) & 15;
                RA[m] = WxyA[k] * exy + RA[m];  RA[m] = WzcA[k] * ezc + RA[m];
                RB[m] = WxyB[k] * exy + RB[m];  RB[m] = WzcB[k] * ezc + RB[m];
            }
            {
                const int m = (j + 9) & 15;
                part1[(s16 + j + 9) & 31][lane] =
                    make_float2(RA[m].x + RA[m].y, RB[m].x + RB[m].y);
            }
        };
        #pragma unroll 1
        for (int tt = 0; tt < 62; ++tt) {
            const int s16 = (tt & 1) << 4;
            __syncthreads();
            #pragma unroll
            for (int j = 0; j < 8; ++j) h1_step(j, s16);
            __syncthreads();
            #pragma unroll
            for (int j = 8; j < 16; ++j) h1_step(j, s16);
        }
        __syncthreads();
        #pragma unroll
        for (int j = 0; j < 8; ++j) h1_step(j, 0);
    }
}

__global__ void reduce_kernel(const float2* __restrict__ ws,
                              float* __restrict__ out) {
    const int tid = threadIdx.x;  // 256 threads
    float sc = 0.f, su = 0.f;
    for (int i = tid; i < N_AGENTS; i += 256) {
        float2 v = ws[i];
        sc += v.x;
        su += v.y;
    }
    #pragma unroll
    for (int off = 32; off > 0; off >>= 1) {
        sc += __shfl_xor(sc, off);
        su += __shfl_xor(su, off);
    }
    __shared__ float2 partw[4];
    int wave = tid >> 6;
    if ((tid & 63) == 0) partw[wave] = make_float2(sc, su);
    __syncthreads();
    if (tid == 0) {
        float SC = partw[0].x + partw[1].x + partw[2].x + partw[3].x;
        float SU = partw[0].y + partw[1].y + partw[2].y + partw[3].y;
        const float invNT  = 1.0f / (float)(N_AGENTS * T_STEPS);
        const float invNT2 = 1.0f / (float)(N_AGENTS * T_STEPS * 2);
        out[0] = -SC * invNT + SU * invNT2;
    }
}

extern "C" void kernel_launch(void* const* d_in, const int* in_sizes, int n_in,
                              void* d_out, int out_size, void* d_ws, size_t ws_size,
                              hipStream_t stream) {
    const float* target_pos = (const float*)d_in[0];
    const float* logsigma   = (const float*)d_in[1];
    const float* x_inits    = (const float*)d_in[2];
    const float* W1         = (const float*)d_in[3];
    const float* b1         = (const float*)d_in[4];
    const float* W2         = (const float*)d_in[5];
    const float* b2         = (const float*)d_in[6];

    float*  pw   = (float*)d_ws;                          // 64 KB packed W1
    float2* sums = (float2*)((char*)d_ws + 64 * 1024);    // per-agent sums

    pack_kernel<<<HIDDEN, 32, 0, stream>>>(W1, pw);
    sim_kernel<<<N_AGENTS, 128, 0, stream>>>(target_pos, logsigma, x_inits,
                                             pw, b1, W2, b2, sums);
    reduce_kernel<<<1, 256, 0, stream>>>(sums, (float*)d_out);
}